// Round 3
// baseline (1799.909 us; speedup 1.0000x reference)
//
#include <hip/hip_runtime.h>
#include <hip/hip_cooperative_groups.h>
#include <math.h>

namespace cg = cooperative_groups;

#define D 128
#define SCAN_B 256   // elements per scan block

typedef __attribute__((ext_vector_type(8))) short bfrag;   // 8 bf16 (4 VGPRs)
typedef __attribute__((ext_vector_type(4))) float ffrag;   // 4 fp32 acc

__device__ inline unsigned short f2bf(float f) {           // RNE fp32->bf16
    unsigned u = __float_as_uint(f);
    u += 0x7FFF + ((u >> 16) & 1);
    return (unsigned short)(u >> 16);
}
__device__ inline float bf2f(unsigned short h) {
    return __uint_as_float(((unsigned)h) << 16);
}
__device__ inline unsigned pack_bf2(float a, float b) {    // [lo=a, hi=b]
    return ((unsigned)f2bf(a)) | (((unsigned)f2bf(b)) << 16);
}

#define ACC8(u) do { \
    a0 += __uint_as_float((u).x << 16); a1 += __uint_as_float((u).x & 0xffff0000u); \
    a2 += __uint_as_float((u).y << 16); a3 += __uint_as_float((u).y & 0xffff0000u); \
    a4 += __uint_as_float((u).z << 16); a5 += __uint_as_float((u).z & 0xffff0000u); \
    a6 += __uint_as_float((u).w << 16); a7 += __uint_as_float((u).w & 0xffff0000u); \
} while (0)

// ================== shared device helpers (used by mega kernel) ==================

// agg[v] = sum_{e: dst=v} h[src[e]] — one wave per node, grid-stride over nodes.
// v3 semantics: wave-uniform trip count, predicated gathers (passing round-2 code).
__device__ __forceinline__ void agg_phase(
        const uint4* __restrict__ h4, const int* __restrict__ row_ptr,
        const int* __restrict__ esrc, uint4* __restrict__ agg4,
        int n_nodes, int wave_gid, int nwaves) {
    const int lane = threadIdx.x & 63;
    const int c = lane & 15;     // uint4 chunk within row
    const int g = lane >> 4;     // edge group 0..3

    for (int node = wave_gid; node < n_nodes; node += nwaves) {
        int beg = row_ptr[node], end = row_ptr[node + 1];
        int deg = end - beg;

        int myidx = 0;
        if (lane < deg) myidx = esrc[beg + lane];   // coalesced: 64 edges, one load

        float a0 = 0.f, a1 = 0.f, a2 = 0.f, a3 = 0.f;
        float a4 = 0.f, a5 = 0.f, a6 = 0.f, a7 = 0.f;

        int nfast = deg < 64 ? deg : 64;
        for (int base = 0; base < nfast; base += 16) {   // UNIFORM trip count
            int p0 = base + g;
            int s0 = __shfl(myidx, p0, 64);
            int s1 = __shfl(myidx, p0 + 4, 64);
            int s2 = __shfl(myidx, p0 + 8, 64);
            int s3 = __shfl(myidx, p0 + 12, 64);
            bool v0 = p0 < nfast;
            bool v1 = (p0 + 4) < nfast;
            bool v2 = (p0 + 8) < nfast;
            bool v3 = (p0 + 12) < nfast;
            uint4 u0, u1, u2, u3;
            if (v0) u0 = h4[(size_t)s0 * 16 + c];
            if (v1) u1 = h4[(size_t)s1 * 16 + c];
            if (v2) u2 = h4[(size_t)s2 * 16 + c];
            if (v3) u3 = h4[(size_t)s3 * 16 + c];
            if (v0) ACC8(u0);
            if (v1) ACC8(u1);
            if (v2) ACC8(u2);
            if (v3) ACC8(u3);
        }
        for (int i = beg + 64 + g; i < end; i += 4) {   // deg>64: ~never
            uint4 u = h4[(size_t)esrc[i] * 16 + c];
            ACC8(u);
        }

        a0 += __shfl_xor(a0, 16, 64); a0 += __shfl_xor(a0, 32, 64);
        a1 += __shfl_xor(a1, 16, 64); a1 += __shfl_xor(a1, 32, 64);
        a2 += __shfl_xor(a2, 16, 64); a2 += __shfl_xor(a2, 32, 64);
        a3 += __shfl_xor(a3, 16, 64); a3 += __shfl_xor(a3, 32, 64);
        a4 += __shfl_xor(a4, 16, 64); a4 += __shfl_xor(a4, 32, 64);
        a5 += __shfl_xor(a5, 16, 64); a5 += __shfl_xor(a5, 32, 64);
        a6 += __shfl_xor(a6, 16, 64); a6 += __shfl_xor(a6, 32, 64);
        a7 += __shfl_xor(a7, 16, 64); a7 += __shfl_xor(a7, 32, 64);

        if (g == 0) {
            uint4 r;
            r.x = pack_bf2(a0, a1);
            r.y = pack_bf2(a2, a3);
            r.z = pack_bf2(a4, a5);
            r.w = pack_bf2(a6, a7);
            agg4[(size_t)node * 16 + c] = r;
        }
    }
}

// y = relu(x @ W^T + b), W-hi from LDS ([128][136] padded rows), W-lo from L2.
__device__ __forceinline__ void linear_phase(
        const unsigned short* __restrict__ x,
        const unsigned short* __restrict__ swhi,   // LDS, row stride 136
        const unsigned short* __restrict__ Wlo,    // global
        const float* __restrict__ b,
        unsigned short* __restrict__ y,
        const float* __restrict__ wout,
        const float* __restrict__ bout,
        float* __restrict__ outp,
        int n_nodes, int fuse_out, int wave_gid, int nwaves) {
    const int lane = threadIdx.x & 63;
    const int col  = lane & 15;
    const int quad = lane >> 4;
    const int ngroups = (n_nodes + 15) >> 4;

    float bvals[8], wvals[8];
    #pragma unroll
    for (int nt = 0; nt < 8; ++nt) {
        bvals[nt] = b[nt * 16 + col];
        wvals[nt] = fuse_out ? wout[nt * 16 + col] : 0.f;
    }
    const float bout0 = fuse_out ? bout[0] : 0.f;

    for (int g = wave_gid; g < ngroups; g += nwaves) {
        int node = g * 16 + col;
        int nload = node < n_nodes ? node : (n_nodes - 1);

        bfrag a[4];
        #pragma unroll
        for (int kt = 0; kt < 4; ++kt)
            a[kt] = *(const bfrag*)(x + (size_t)nload * D + kt * 32 + quad * 8);

        float part0 = 0.f, part1 = 0.f, part2 = 0.f, part3 = 0.f;

        #pragma unroll
        for (int nt = 0; nt < 8; ++nt) {
            ffrag c = {0.f, 0.f, 0.f, 0.f};
            #pragma unroll
            for (int kt = 0; kt < 4; ++kt) {
                bfrag bh = *(const bfrag*)&swhi[(nt * 16 + col) * 136 + kt * 32 + quad * 8];
                bfrag bl = *(const bfrag*)(Wlo + (size_t)(nt * 16 + col) * D + kt * 32 + quad * 8);
                c = __builtin_amdgcn_mfma_f32_16x16x32_bf16(a[kt], bh, c, 0, 0, 0);
                c = __builtin_amdgcn_mfma_f32_16x16x32_bf16(a[kt], bl, c, 0, 0, 0);
            }
            if (fuse_out) {
                part0 += fmaxf(c[0] + bvals[nt], 0.f) * wvals[nt];
                part1 += fmaxf(c[1] + bvals[nt], 0.f) * wvals[nt];
                part2 += fmaxf(c[2] + bvals[nt], 0.f) * wvals[nt];
                part3 += fmaxf(c[3] + bvals[nt], 0.f) * wvals[nt];
            } else {
                #pragma unroll
                for (int r = 0; r < 4; ++r) {
                    int onode = g * 16 + quad * 4 + r;
                    if (onode < n_nodes)
                        y[(size_t)onode * D + nt * 16 + col] =
                            f2bf(fmaxf(c[r] + bvals[nt], 0.f));
                }
            }
        }

        if (fuse_out) {
            float part[4] = {part0, part1, part2, part3};
            #pragma unroll
            for (int r = 0; r < 4; ++r) {
                float s = part[r];
                s += __shfl_xor(s, 1, 64);
                s += __shfl_xor(s, 2, 64);
                s += __shfl_xor(s, 4, 64);
                s += __shfl_xor(s, 8, 64);
                int onode = g * 16 + quad * 4 + r;
                if (col == 0 && onode < n_nodes)
                    outp[onode] = 1.0f / (1.0f + expf(-(s + bout0)));
            }
        }
    }
}

// ================== cooperative mega kernel ==================

struct MegaParams {
    const int* cncpt_ids; const int* src; const int* dst;
    const float* emb;
    const float* W1; const float* b1;
    const float* W2; const float* b2;
    const float* Wout; const float* bout;
    float* out;
    unsigned short* bufA; unsigned short* bufB;
    unsigned short* W1hi; unsigned short* W1lo;
    unsigned short* W2hi; unsigned short* W2lo;
    int* deg; int* row_ptr; int* cursor; int* blocksums; int* esrc;
    int n_nodes; int n_edges;
};

union __align__(16) SMem {
    int scan[512];
    unsigned short w[128 * 136];   // 34816 B -> 4 blocks/CU
};

__device__ __forceinline__ void stage_whi(unsigned short* w,
                                          const unsigned short* __restrict__ Whi) {
    const uint4* s4 = (const uint4*)Whi;
    #pragma unroll
    for (int j = 0; j < 8; ++j) {
        int ch = (int)threadIdx.x + j * 256;   // 2048 chunks of 16B
        int row = ch >> 4, k8 = ch & 15;
        *(uint4*)&w[row * 136 + k8 * 8] = s4[ch];
    }
}

__global__ __launch_bounds__(256, 4) void mega_kernel(MegaParams p) {
    __shared__ SMem sm;
    cg::grid_group grd = cg::this_grid();
    const int tid  = threadIdx.x;
    const int gtid = (int)blockIdx.x * 256 + tid;
    const int gsz  = (int)gridDim.x * 256;
    const int wave_gid = gtid >> 6;
    const int nwaves   = gsz >> 6;
    const int np1 = p.n_nodes + 1;
    const int nb  = (np1 + SCAN_B - 1) / SCAN_B;

    // ---- A1: W split + zero deg + gather h0 ----
    for (int i = gtid; i < D * D; i += gsz) {
        float f1 = p.W1[i];
        unsigned short h1 = f2bf(f1);
        p.W1hi[i] = h1;
        p.W1lo[i] = f2bf(f1 - bf2f(h1));
        float f2 = p.W2[i];
        unsigned short h2 = f2bf(f2);
        p.W2hi[i] = h2;
        p.W2lo[i] = f2bf(f2 - bf2f(h2));
    }
    for (int i = gtid; i < np1; i += gsz) p.deg[i] = 0;
    for (int idx = gtid; idx < p.n_nodes * 16; idx += gsz) {
        int node = idx >> 4;
        int c = idx & 15;
        size_t cid = (size_t)p.cncpt_ids[node];
        const float4* s = (const float4*)(p.emb + cid * D) + c * 2;
        float4 v0 = s[0];
        float4 v1 = s[1];
        uint4 pk;
        pk.x = pack_bf2(v0.x, v0.y);
        pk.y = pack_bf2(v0.z, v0.w);
        pk.z = pack_bf2(v1.x, v1.y);
        pk.w = pack_bf2(v1.z, v1.w);
        ((uint4*)p.bufA)[(size_t)node * 16 + c] = pk;
    }
    __threadfence();
    grd.sync();

    // ---- A2: degree count ----
    for (int e = gtid; e < p.n_edges; e += gsz) atomicAdd(&p.deg[p.dst[e]], 1);
    __threadfence();
    grd.sync();

    // ---- B: per-block exclusive scans ----
    for (int vb = (int)blockIdx.x; vb < nb; vb += (int)gridDim.x) {
        int i = vb * SCAN_B + tid;
        int v = (i < np1) ? p.deg[i] : 0;
        sm.scan[tid] = v;
        __syncthreads();
        #pragma unroll
        for (int off = 1; off < SCAN_B; off <<= 1) {
            int t = (tid >= off) ? sm.scan[tid - off] : 0;
            __syncthreads();
            sm.scan[tid] += t;
            __syncthreads();
        }
        if (i < np1) p.row_ptr[i] = sm.scan[tid] - v;          // exclusive
        if (tid == SCAN_B - 1) p.blocksums[vb] = sm.scan[SCAN_B - 1];
        __syncthreads();
    }
    __threadfence();
    grd.sync();

    // ---- C: scan of blocksums (block 0, chunked 256) ----
    if (blockIdx.x == 0) {
        int carry = 0;
        for (int c0 = 0; c0 < nb; c0 += 256) {
            int i = c0 + tid;
            int v = (i < nb) ? p.blocksums[i] : 0;
            sm.scan[tid] = v;
            __syncthreads();
            #pragma unroll
            for (int off = 1; off < 256; off <<= 1) {
                int t = (tid >= off) ? sm.scan[tid - off] : 0;
                __syncthreads();
                sm.scan[tid] += t;
                __syncthreads();
            }
            if (i < nb) p.blocksums[i] = sm.scan[tid] - v + carry;  // exclusive
            carry += sm.scan[255];
            __syncthreads();
        }
    }
    __threadfence();
    grd.sync();

    // ---- D: add offsets + init cursor ----
    for (int i = gtid; i < np1; i += gsz) {
        int rp = p.row_ptr[i] + p.blocksums[i / SCAN_B];
        p.row_ptr[i] = rp;
        if (i < p.n_nodes) p.cursor[i] = rp;
    }
    __threadfence();
    grd.sync();

    // ---- E: csr fill ----
    for (int e = gtid; e < p.n_edges; e += gsz) {
        int pos = atomicAdd(&p.cursor[p.dst[e]], 1);
        p.esrc[pos] = p.src[e];
    }
    __threadfence();
    grd.sync();

    // ---- F: agg layer 1 (bufA -> bufB) ----
    agg_phase((const uint4*)p.bufA, p.row_ptr, p.esrc, (uint4*)p.bufB,
              p.n_nodes, wave_gid, nwaves);
    __threadfence();
    grd.sync();

    // ---- G: linear layer 1 (bufB -> bufA) ----
    stage_whi(sm.w, p.W1hi);
    __syncthreads();
    linear_phase(p.bufB, sm.w, p.W1lo, p.b1, p.bufA,
                 nullptr, nullptr, nullptr, p.n_nodes, 0, wave_gid, nwaves);
    __threadfence();
    grd.sync();

    // ---- H: agg layer 2 (bufA -> bufB) ----
    agg_phase((const uint4*)p.bufA, p.row_ptr, p.esrc, (uint4*)p.bufB,
              p.n_nodes, wave_gid, nwaves);
    __threadfence();
    grd.sync();

    // ---- I: linear layer 2 + fused head (bufB -> out) ----
    stage_whi(sm.w, p.W2hi);
    __syncthreads();
    linear_phase(p.bufB, sm.w, p.W2lo, p.b2, nullptr,
                 p.Wout, p.bout, p.out, p.n_nodes, 1, wave_gid, nwaves);
}

// ================== fallback multi-kernel path (round-2, passing) ==================

__global__ void setup1_kernel(const float* __restrict__ W1,
                              const float* __restrict__ W2,
                              unsigned short* __restrict__ hi1,
                              unsigned short* __restrict__ lo1,
                              unsigned short* __restrict__ hi2,
                              unsigned short* __restrict__ lo2,
                              int* __restrict__ deg, int np1, int nblk_w) {
    if ((int)blockIdx.x < nblk_w) {
        int i = blockIdx.x * blockDim.x + threadIdx.x;
        if (i < D * D) {
            float f1 = W1[i];
            unsigned short h1 = f2bf(f1);
            hi1[i] = h1;
            lo1[i] = f2bf(f1 - bf2f(h1));
            float f2 = W2[i];
            unsigned short h2 = f2bf(f2);
            hi2[i] = h2;
            lo2[i] = f2bf(f2 - bf2f(h2));
        }
    } else {
        int i = ((int)blockIdx.x - nblk_w) * blockDim.x + threadIdx.x;
        if (i < np1) deg[i] = 0;
    }
}

__global__ void setup2_kernel(const float* __restrict__ emb,
                              const int* __restrict__ ids,
                              uint4* __restrict__ h4,
                              const int* __restrict__ dst,
                              int* __restrict__ deg,
                              int n_nodes, int n_edges, int nblk_g) {
    if ((int)blockIdx.x < nblk_g) {
        int idx = blockIdx.x * blockDim.x + threadIdx.x;
        int total = n_nodes * 16;
        if (idx >= total) return;
        int node = idx >> 4;
        int c = idx & 15;
        size_t cid = (size_t)ids[node];
        const float4* s = (const float4*)(emb + cid * D) + c * 2;
        float4 v0 = s[0];
        float4 v1 = s[1];
        uint4 pk;
        pk.x = pack_bf2(v0.x, v0.y);
        pk.y = pack_bf2(v0.z, v0.w);
        pk.z = pack_bf2(v1.x, v1.y);
        pk.w = pack_bf2(v1.z, v1.w);
        h4[(size_t)node * 16 + c] = pk;
    } else {
        int e = ((int)blockIdx.x - nblk_g) * blockDim.x + threadIdx.x;
        if (e < n_edges) atomicAdd(&deg[dst[e]], 1);
    }
}

__global__ __launch_bounds__(SCAN_B) void scan_block_kernel(
        const int* __restrict__ deg, int* __restrict__ row_ptr,
        int* __restrict__ blocksums, int n) {
    __shared__ int s[SCAN_B];
    int i = blockIdx.x * SCAN_B + threadIdx.x;
    int v = (i < n) ? deg[i] : 0;
    s[threadIdx.x] = v;
    __syncthreads();
    #pragma unroll
    for (int off = 1; off < SCAN_B; off <<= 1) {
        int t = (threadIdx.x >= off) ? s[threadIdx.x - off] : 0;
        __syncthreads();
        s[threadIdx.x] += t;
        __syncthreads();
    }
    if (i < n) row_ptr[i] = s[threadIdx.x] - v;
    if (threadIdx.x == SCAN_B - 1) blocksums[blockIdx.x] = s[SCAN_B - 1];
}

__global__ __launch_bounds__(512) void scan_sums_kernel(int* __restrict__ blocksums,
                                                        int nb) {
    __shared__ int s[512];
    int v = (threadIdx.x < nb) ? blocksums[threadIdx.x] : 0;
    s[threadIdx.x] = v;
    __syncthreads();
    #pragma unroll
    for (int off = 1; off < 512; off <<= 1) {
        int t = (threadIdx.x >= off) ? s[threadIdx.x - off] : 0;
        __syncthreads();
        s[threadIdx.x] += t;
        __syncthreads();
    }
    if (threadIdx.x < nb) blocksums[threadIdx.x] = s[threadIdx.x] - v;
}

__global__ void add_offsets_kernel(int* __restrict__ row_ptr,
                                   const int* __restrict__ blocksums,
                                   int* __restrict__ cursor, int n, int n_nodes) {
    int i = blockIdx.x * blockDim.x + threadIdx.x;
    if (i >= n) return;
    int rp = row_ptr[i] + blocksums[i / SCAN_B];
    row_ptr[i] = rp;
    if (i < n_nodes) cursor[i] = rp;
}

__global__ void csr_fill_kernel(const int* __restrict__ src,
                                const int* __restrict__ dst,
                                int* __restrict__ cursor,
                                int* __restrict__ esrc, int n_edges) {
    int e = blockIdx.x * blockDim.x + threadIdx.x;
    if (e >= n_edges) return;
    int pos = atomicAdd(&cursor[dst[e]], 1);
    esrc[pos] = src[e];
}

__global__ __launch_bounds__(256) void agg_kernel(
        const uint4* __restrict__ h4, const int* __restrict__ row_ptr,
        const int* __restrict__ esrc, uint4* __restrict__ agg4, int n_nodes) {
    int wave_gid = (int)(blockIdx.x * 4 + (threadIdx.x >> 6));
    if (wave_gid >= n_nodes) return;
    agg_phase(h4, row_ptr, esrc, agg4, n_nodes, wave_gid, (int)gridDim.x * 4);
}

__global__ __launch_bounds__(256) void linear_mfma_kernel(
        const unsigned short* __restrict__ x,
        const unsigned short* __restrict__ Whi,
        const unsigned short* __restrict__ Wlo,
        const float* __restrict__ b,
        unsigned short* __restrict__ y,
        const float* __restrict__ wout,
        const float* __restrict__ bout,
        float* __restrict__ outp,
        int n_nodes, int fuse_out) {
    __shared__ __align__(16) unsigned short sW[128 * 136];
    stage_whi(sW, Whi);
    __syncthreads();
    int wave_gid = (int)(blockIdx.x * 4 + (threadIdx.x >> 6));
    linear_phase(x, sW, Wlo, b, y, wout, bout, outp, n_nodes, fuse_out,
                 wave_gid, (int)gridDim.x * 4);
}

// ================== host launcher ==================

extern "C" void kernel_launch(void* const* d_in, const int* in_sizes, int n_in,
                              void* d_out, int out_size, void* d_ws, size_t ws_size,
                              hipStream_t stream) {
    const int*   cncpt_ids = (const int*)d_in[0];
    const int*   src       = (const int*)d_in[1];
    const int*   dst       = (const int*)d_in[2];
    const float* emb       = (const float*)d_in[3];
    const float* W1        = (const float*)d_in[4];
    const float* b1        = (const float*)d_in[5];
    const float* W2        = (const float*)d_in[6];
    const float* b2        = (const float*)d_in[7];
    const float* Wout      = (const float*)d_in[8];
    const float* bout      = (const float*)d_in[9];
    float* out = (float*)d_out;

    const int n_nodes = in_sizes[0];
    const int n_edges = in_sizes[1];

    // ---- workspace carve-up ----
    unsigned short* bufA = (unsigned short*)d_ws;          // N*D bf16
    unsigned short* bufB = bufA + (size_t)n_nodes * D;     // N*D bf16
    int*   deg      = (int*)(bufB + (size_t)n_nodes * D);  // N+1 ints
    int*   row_ptr  = deg + (n_nodes + 1);                 // N+1 ints
    int*   cursor   = row_ptr + (n_nodes + 1);             // N ints
    int*   blocksums= cursor + n_nodes;                    // 512 ints
    int*   esrc     = blocksums + 512;                     // E ints
    size_t walign   = ((size_t)(esrc + n_edges) + 15) & ~(size_t)15;
    unsigned short* W1hi = (unsigned short*)walign;        // D*D each
    unsigned short* W1lo = W1hi + D * D;
    unsigned short* W2hi = W1lo + D * D;
    unsigned short* W2lo = W2hi + D * D;

    const int np1 = n_nodes + 1;
    const int nb_scan = (np1 + SCAN_B - 1) / SCAN_B;

    // ---- preferred: one cooperative mega-kernel ----
    MegaParams p;
    p.cncpt_ids = cncpt_ids; p.src = src; p.dst = dst; p.emb = emb;
    p.W1 = W1; p.b1 = b1; p.W2 = W2; p.b2 = b2; p.Wout = Wout; p.bout = bout;
    p.out = out;
    p.bufA = bufA; p.bufB = bufB;
    p.W1hi = W1hi; p.W1lo = W1lo; p.W2hi = W2hi; p.W2lo = W2lo;
    p.deg = deg; p.row_ptr = row_ptr; p.cursor = cursor;
    p.blocksums = blocksums; p.esrc = esrc;
    p.n_nodes = n_nodes; p.n_edges = n_edges;

    int maxb = 0;
    hipError_t oerr = hipOccupancyMaxActiveBlocksPerMultiprocessor(
        &maxb, mega_kernel, 256, 0);
    int grid = (oerr == hipSuccess && maxb > 0) ? maxb * 256 : 512;
    if (grid > 2048) grid = 2048;

    void* args[] = {(void*)&p};
    hipError_t lerr = hipLaunchCooperativeKernel(
        mega_kernel, dim3(grid), dim3(256), args, 0, stream);
    if (lerr == hipSuccess) return;

    // ---- fallback: round-2 multi-kernel path ----
    const int nblk_w = (D * D + 255) / 256;
    const int nblk_z = (np1 + 255) / 256;
    setup1_kernel<<<nblk_w + nblk_z, 256, 0, stream>>>(
        W1, W2, W1hi, W1lo, W2hi, W2lo, deg, np1, nblk_w);

    const int nblk_g = (n_nodes * 16 + 255) / 256;
    const int nblk_d = (n_edges + 255) / 256;
    setup2_kernel<<<nblk_g + nblk_d, 256, 0, stream>>>(
        emb, cncpt_ids, (uint4*)bufA, dst, deg, n_nodes, n_edges, nblk_g);

    scan_block_kernel<<<nb_scan, SCAN_B, 0, stream>>>(deg, row_ptr, blocksums, np1);
    scan_sums_kernel<<<1, 512, 0, stream>>>(blocksums, nb_scan);
    add_offsets_kernel<<<(np1 + 255) / 256, 256, 0, stream>>>(
        row_ptr, blocksums, cursor, np1, n_nodes);
    csr_fill_kernel<<<nblk_d, 256, 0, stream>>>(src, dst, cursor, esrc, n_edges);

    const int agg_grid = (n_nodes + 3) / 4;
    const int ngroups = (n_nodes + 15) / 16;
    const int lin_grid = (ngroups + 7) / 8;

    agg_kernel<<<agg_grid, 256, 0, stream>>>(
        (const uint4*)bufA, row_ptr, esrc, (uint4*)bufB, n_nodes);
    linear_mfma_kernel<<<lin_grid, 256, 0, stream>>>(
        bufB, W1hi, W1lo, b1, bufA, nullptr, nullptr, nullptr, n_nodes, 0);

    agg_kernel<<<agg_grid, 256, 0, stream>>>(
        (const uint4*)bufA, row_ptr, esrc, (uint4*)bufB, n_nodes);
    linear_mfma_kernel<<<lin_grid, 256, 0, stream>>>(
        bufB, W2hi, W2lo, b2, nullptr, Wout, bout, out, n_nodes, 1);
}

// Round 4
// 866.335 us; speedup vs baseline: 2.0776x; 2.0776x over previous
//
#include <hip/hip_runtime.h>
#include <math.h>

#define D 128
#define SCAN_B 256   // elements per scan block

typedef __attribute__((ext_vector_type(8))) short bfrag;   // 8 bf16 (4 VGPRs)
typedef __attribute__((ext_vector_type(4))) float ffrag;   // 4 fp32 acc

__device__ inline unsigned short f2bf(float f) {           // RNE fp32->bf16
    unsigned u = __float_as_uint(f);
    u += 0x7FFF + ((u >> 16) & 1);
    return (unsigned short)(u >> 16);
}
__device__ inline float bf2f(unsigned short h) {
    return __uint_as_float(((unsigned)h) << 16);
}
__device__ inline unsigned pack_bf2(float a, float b) {    // [lo=a, hi=b]
    return ((unsigned)f2bf(a)) | (((unsigned)f2bf(b)) << 16);
}

// XOR-swizzle (T2): off in shorts, multiples of 8 (16B units); keeps 16B align.
#define XSWZ(row, off) ((off) ^ (((row) & 7) << 3))

#define ACC8(u) do { \
    a0 += __uint_as_float((u).x << 16); a1 += __uint_as_float((u).x & 0xffff0000u); \
    a2 += __uint_as_float((u).y << 16); a3 += __uint_as_float((u).y & 0xffff0000u); \
    a4 += __uint_as_float((u).z << 16); a5 += __uint_as_float((u).z & 0xffff0000u); \
    a6 += __uint_as_float((u).w << 16); a7 += __uint_as_float((u).w & 0xffff0000u); \
} while (0)

// ---------------- setup1: zero deg + work counters + split W1,W2 -> bf16 hi/lo ----
__global__ void setup1_kernel(const float* __restrict__ W1,
                              const float* __restrict__ W2,
                              unsigned short* __restrict__ hi1,
                              unsigned short* __restrict__ lo1,
                              unsigned short* __restrict__ hi2,
                              unsigned short* __restrict__ lo2,
                              int* __restrict__ deg, int* __restrict__ wcnt,
                              int np1, int nblk_w) {
    if ((int)blockIdx.x < nblk_w) {
        int i = blockIdx.x * blockDim.x + threadIdx.x;
        if (i < D * D) {
            float f1 = W1[i];
            unsigned short h1 = f2bf(f1);
            hi1[i] = h1;
            lo1[i] = f2bf(f1 - bf2f(h1));
            float f2 = W2[i];
            unsigned short h2 = f2bf(f2);
            hi2[i] = h2;
            lo2[i] = f2bf(f2 - bf2f(h2));
        }
    } else {
        int i = ((int)blockIdx.x - nblk_w) * blockDim.x + threadIdx.x;
        if (i < np1) deg[i] = 0;
        if (i < 2) wcnt[i] = 0;
    }
}

// ---------------- setup2: h0 = bf16(emb[ids]) + degree count ----------------
__global__ void setup2_kernel(const float* __restrict__ emb,
                              const int* __restrict__ ids,
                              uint4* __restrict__ h4,
                              const int* __restrict__ dst,
                              int* __restrict__ deg,
                              int n_nodes, int n_edges, int nblk_g) {
    if ((int)blockIdx.x < nblk_g) {
        int idx = blockIdx.x * blockDim.x + threadIdx.x;
        int total = n_nodes * 16;
        if (idx >= total) return;
        int node = idx >> 4;
        int c = idx & 15;
        size_t cid = (size_t)ids[node];
        const float4* s = (const float4*)(emb + cid * D) + c * 2;
        float4 v0 = s[0];
        float4 v1 = s[1];
        uint4 p;
        p.x = pack_bf2(v0.x, v0.y);
        p.y = pack_bf2(v0.z, v0.w);
        p.z = pack_bf2(v1.x, v1.y);
        p.w = pack_bf2(v1.z, v1.w);
        h4[(size_t)node * 16 + c] = p;
    } else {
        int e = ((int)blockIdx.x - nblk_g) * blockDim.x + threadIdx.x;
        if (e < n_edges) atomicAdd(&deg[dst[e]], 1);
    }
}

// ---------------- CSR scan pipeline (verified round-2 code) ----------------
__global__ __launch_bounds__(SCAN_B) void scan_block_kernel(
        const int* __restrict__ deg, int* __restrict__ row_ptr,
        int* __restrict__ blocksums, int n) {
    __shared__ int s[SCAN_B];
    int i = blockIdx.x * SCAN_B + threadIdx.x;
    int v = (i < n) ? deg[i] : 0;
    s[threadIdx.x] = v;
    __syncthreads();
    #pragma unroll
    for (int off = 1; off < SCAN_B; off <<= 1) {
        int t = (threadIdx.x >= off) ? s[threadIdx.x - off] : 0;
        __syncthreads();
        s[threadIdx.x] += t;
        __syncthreads();
    }
    if (i < n) row_ptr[i] = s[threadIdx.x] - v;      // exclusive
    if (threadIdx.x == SCAN_B - 1) blocksums[blockIdx.x] = s[SCAN_B - 1];
}

__global__ __launch_bounds__(512) void scan_sums_kernel(int* __restrict__ blocksums,
                                                        int nb) {
    __shared__ int s[512];
    int v = (threadIdx.x < nb) ? blocksums[threadIdx.x] : 0;
    s[threadIdx.x] = v;
    __syncthreads();
    #pragma unroll
    for (int off = 1; off < 512; off <<= 1) {
        int t = (threadIdx.x >= off) ? s[threadIdx.x - off] : 0;
        __syncthreads();
        s[threadIdx.x] += t;
        __syncthreads();
    }
    if (threadIdx.x < nb) blocksums[threadIdx.x] = s[threadIdx.x] - v;  // exclusive
}

__global__ void add_offsets_kernel(int* __restrict__ row_ptr,
                                   const int* __restrict__ blocksums,
                                   int* __restrict__ cursor, int n, int n_nodes) {
    int i = blockIdx.x * blockDim.x + threadIdx.x;
    if (i >= n) return;
    int rp = row_ptr[i] + blocksums[i / SCAN_B];
    row_ptr[i] = rp;
    if (i < n_nodes) cursor[i] = rp;
}

__global__ void csr_fill_kernel(const int* __restrict__ src,
                                const int* __restrict__ dst,
                                int* __restrict__ cursor,
                                int* __restrict__ esrc, int n_edges) {
    int e = blockIdx.x * blockDim.x + threadIdx.x;
    if (e >= n_edges) return;
    int pos = atomicAdd(&cursor[dst[e]], 1);
    esrc[pos] = src[e];
}

// ---------------- fused layer: agg(16 nodes)->LDS, then MFMA linear ----------------
// 512 threads = 8 independent waves sharing LDS W-hi (XOR-swizzled [128][128]).
// Each wave: steals a 16-node group (global atomic), aggregates each node with the
// verified gather (now 8 loads in flight), writes bf16 rows into its private
// swizzled x-tile, waits lgkmcnt, then runs the verified MFMA linear with A-frags
// from LDS. No __syncthreads in the work loop (waves have different trip counts).
__global__ __launch_bounds__(512, 4) void fused_layer_kernel(
        const uint4* __restrict__ h4,
        const int* __restrict__ row_ptr,
        const int* __restrict__ esrc,
        const unsigned short* __restrict__ Whi,
        const unsigned short* __restrict__ Wlo,
        const float* __restrict__ b,
        unsigned short* __restrict__ y,
        const float* __restrict__ wout,
        const float* __restrict__ bout,
        float* __restrict__ outp,
        int* __restrict__ wcnt,
        int n_nodes, int fuse_out) {
    __shared__ __align__(16) unsigned short sW[128 * 128];   // 32 KiB, swizzled
    __shared__ __align__(16) unsigned short sX[8][16 * 128]; // 32 KiB, swizzled

    const int tid = threadIdx.x;
    {   // stage W-hi: 2048 16B chunks over 512 threads
        const uint4* s4 = (const uint4*)Whi;
        #pragma unroll
        for (int j = 0; j < 4; ++j) {
            int ch = tid + j * 512;
            int row = ch >> 4, k8 = ch & 15;
            *(uint4*)&sW[row * 128 + XSWZ(row, k8 * 8)] = s4[ch];
        }
    }
    __syncthreads();

    const int wid  = tid >> 6;
    const int lane = tid & 63;
    const int c    = lane & 15;    // 16B chunk within a 256B row / MFMA col
    const int g    = lane >> 4;    // edge group / MFMA quad
    unsigned short* xt = &sX[wid][0];
    const int ngroups = (n_nodes + 15) >> 4;

    float bvals[8], wvals[8];
    #pragma unroll
    for (int nt = 0; nt < 8; ++nt) {
        bvals[nt] = b[nt * 16 + c];
        wvals[nt] = fuse_out ? wout[nt * 16 + c] : 0.f;
    }
    const float bout0 = fuse_out ? bout[0] : 0.f;

    for (;;) {
        int grp;
        if (lane == 0) grp = atomicAdd(wcnt, 1);
        grp = __shfl(grp, 0, 64);
        if (grp >= ngroups) break;

        // ---- aggregate the group's 16 nodes into xt ----
        for (int j = 0; j < 16; ++j) {
            int node = grp * 16 + j;
            int beg = 0, end = 0;
            if (node < n_nodes) { beg = row_ptr[node]; end = row_ptr[node + 1]; }
            int deg = end - beg;
            int myidx = 0;
            if (lane < deg) myidx = esrc[beg + lane];   // coalesced 64-edge load

            float a0 = 0.f, a1 = 0.f, a2 = 0.f, a3 = 0.f;
            float a4 = 0.f, a5 = 0.f, a6 = 0.f, a7 = 0.f;

            int nfast = deg < 64 ? deg : 64;
            for (int base = 0; base < nfast; base += 32) {  // UNIFORM trip count
                int p0 = base + g;           // <= 35
                int p4 = p0 + 16;            // <= 51; +12 <= 63: full-wave shfl ok
                int s0 = __shfl(myidx, p0, 64);
                int s1 = __shfl(myidx, p0 + 4, 64);
                int s2 = __shfl(myidx, p0 + 8, 64);
                int s3 = __shfl(myidx, p0 + 12, 64);
                int s4i = __shfl(myidx, p4, 64);
                int s5 = __shfl(myidx, p4 + 4, 64);
                int s6 = __shfl(myidx, p4 + 8, 64);
                int s7 = __shfl(myidx, p4 + 12, 64);
                bool v0 = p0 < nfast;
                bool v1 = (p0 + 4) < nfast;
                bool v2 = (p0 + 8) < nfast;
                bool v3 = (p0 + 12) < nfast;
                bool v4 = p4 < nfast;
                bool v5 = (p4 + 4) < nfast;
                bool v6 = (p4 + 8) < nfast;
                bool v7 = (p4 + 12) < nfast;
                uint4 u0, u1, u2, u3, u4, u5, u6, u7;
                if (v0) u0 = h4[(size_t)s0 * 16 + c];
                if (v1) u1 = h4[(size_t)s1 * 16 + c];
                if (v2) u2 = h4[(size_t)s2 * 16 + c];
                if (v3) u3 = h4[(size_t)s3 * 16 + c];
                if (v4) u4 = h4[(size_t)s4i * 16 + c];
                if (v5) u5 = h4[(size_t)s5 * 16 + c];
                if (v6) u6 = h4[(size_t)s6 * 16 + c];
                if (v7) u7 = h4[(size_t)s7 * 16 + c];
                if (v0) ACC8(u0);
                if (v1) ACC8(u1);
                if (v2) ACC8(u2);
                if (v3) ACC8(u3);
                if (v4) ACC8(u4);
                if (v5) ACC8(u5);
                if (v6) ACC8(u6);
                if (v7) ACC8(u7);
            }
            for (int i = beg + 64 + g; i < end; i += 4) {   // deg>64: ~never
                uint4 u = h4[(size_t)esrc[i] * 16 + c];
                ACC8(u);
            }

            a0 += __shfl_xor(a0, 16, 64); a0 += __shfl_xor(a0, 32, 64);
            a1 += __shfl_xor(a1, 16, 64); a1 += __shfl_xor(a1, 32, 64);
            a2 += __shfl_xor(a2, 16, 64); a2 += __shfl_xor(a2, 32, 64);
            a3 += __shfl_xor(a3, 16, 64); a3 += __shfl_xor(a3, 32, 64);
            a4 += __shfl_xor(a4, 16, 64); a4 += __shfl_xor(a4, 32, 64);
            a5 += __shfl_xor(a5, 16, 64); a5 += __shfl_xor(a5, 32, 64);
            a6 += __shfl_xor(a6, 16, 64); a6 += __shfl_xor(a6, 32, 64);
            a7 += __shfl_xor(a7, 16, 64); a7 += __shfl_xor(a7, 32, 64);

            if (g == 0) {
                uint4 r;
                r.x = pack_bf2(a0, a1);
                r.y = pack_bf2(a2, a3);
                r.z = pack_bf2(a4, a5);
                r.w = pack_bf2(a6, a7);
                *(uint4*)&xt[j * 128 + XSWZ(j, c * 8)] = r;
            }
        }
        // drain this wave's LDS queue: xt writes (lanes 0-15) visible to all lanes
        __asm__ volatile("s_waitcnt lgkmcnt(0)" ::: "memory");

        // ---- MFMA linear on the x-tile ----
        bfrag a[4];
        #pragma unroll
        for (int kt = 0; kt < 4; ++kt)
            a[kt] = *(const bfrag*)&xt[c * 128 + XSWZ(c, kt * 32 + g * 8)];

        float part0 = 0.f, part1 = 0.f, part2 = 0.f, part3 = 0.f;

        #pragma unroll
        for (int nt = 0; nt < 8; ++nt) {
            ffrag cc = {0.f, 0.f, 0.f, 0.f};
            #pragma unroll
            for (int kt = 0; kt < 4; ++kt) {
                int o = nt * 16 + c;
                bfrag bh = *(const bfrag*)&sW[o * 128 + XSWZ(o, kt * 32 + g * 8)];
                bfrag bl = *(const bfrag*)(Wlo + (size_t)o * D + kt * 32 + g * 8);
                cc = __builtin_amdgcn_mfma_f32_16x16x32_bf16(a[kt], bh, cc, 0, 0, 0);
                cc = __builtin_amdgcn_mfma_f32_16x16x32_bf16(a[kt], bl, cc, 0, 0, 0);
            }
            // C layout: value r is C[row = g*4 + r][c]
            if (fuse_out) {
                part0 += fmaxf(cc[0] + bvals[nt], 0.f) * wvals[nt];
                part1 += fmaxf(cc[1] + bvals[nt], 0.f) * wvals[nt];
                part2 += fmaxf(cc[2] + bvals[nt], 0.f) * wvals[nt];
                part3 += fmaxf(cc[3] + bvals[nt], 0.f) * wvals[nt];
            } else {
                #pragma unroll
                for (int r = 0; r < 4; ++r) {
                    int onode = grp * 16 + g * 4 + r;
                    if (onode < n_nodes)
                        y[(size_t)onode * D + nt * 16 + c] =
                            f2bf(fmaxf(cc[r] + bvals[nt], 0.f));
                }
            }
        }

        if (fuse_out) {
            float part[4] = {part0, part1, part2, part3};
            #pragma unroll
            for (int r = 0; r < 4; ++r) {
                float s = part[r];
                s += __shfl_xor(s, 1, 64);
                s += __shfl_xor(s, 2, 64);
                s += __shfl_xor(s, 4, 64);
                s += __shfl_xor(s, 8, 64);   // reduce over 16 cols within quad
                int onode = grp * 16 + g * 4 + r;
                if (c == 0 && onode < n_nodes)
                    outp[onode] = 1.0f / (1.0f + expf(-(s + bout0)));
            }
        }
    }
}

// ================== host launcher ==================

extern "C" void kernel_launch(void* const* d_in, const int* in_sizes, int n_in,
                              void* d_out, int out_size, void* d_ws, size_t ws_size,
                              hipStream_t stream) {
    const int*   cncpt_ids = (const int*)d_in[0];
    const int*   src       = (const int*)d_in[1];
    const int*   dst       = (const int*)d_in[2];
    const float* emb       = (const float*)d_in[3];
    const float* W1        = (const float*)d_in[4];
    const float* b1        = (const float*)d_in[5];
    const float* W2        = (const float*)d_in[6];
    const float* b2        = (const float*)d_in[7];
    const float* Wout      = (const float*)d_in[8];
    const float* bout      = (const float*)d_in[9];
    float* out = (float*)d_out;

    const int n_nodes = in_sizes[0];
    const int n_edges = in_sizes[1];

    // ---- workspace carve-up ----
    unsigned short* bufA = (unsigned short*)d_ws;          // N*D bf16
    unsigned short* bufB = bufA + (size_t)n_nodes * D;     // N*D bf16
    int*   deg      = (int*)(bufB + (size_t)n_nodes * D);  // N+1 ints
    int*   row_ptr  = deg + (n_nodes + 1);                 // N+1 ints
    int*   cursor   = row_ptr + (n_nodes + 1);             // N ints
    int*   blocksums= cursor + n_nodes;                    // 512 ints (scan uses <=391)
    int*   wcnt     = blocksums + 504;                     // 2 work counters
    int*   esrc     = blocksums + 512;                     // E ints
    size_t walign   = ((size_t)(esrc + n_edges) + 15) & ~(size_t)15;
    unsigned short* W1hi = (unsigned short*)walign;        // D*D each
    unsigned short* W1lo = W1hi + D * D;
    unsigned short* W2hi = W1lo + D * D;
    unsigned short* W2lo = W2hi + D * D;

    const int np1 = n_nodes + 1;
    const int nb_scan = (np1 + SCAN_B - 1) / SCAN_B;

    // ---- setup1: zero deg + counters + weight splits ----
    const int nblk_w = (D * D + 255) / 256;
    const int nblk_z = (np1 + 255) / 256;
    setup1_kernel<<<nblk_w + nblk_z, 256, 0, stream>>>(
        W1, W2, W1hi, W1lo, W2hi, W2lo, deg, wcnt, np1, nblk_w);

    // ---- setup2: gather h0 + degree count ----
    const int nblk_g = (n_nodes * 16 + 255) / 256;
    const int nblk_d = (n_edges + 255) / 256;
    setup2_kernel<<<nblk_g + nblk_d, 256, 0, stream>>>(
        emb, cncpt_ids, (uint4*)bufA, dst, deg, n_nodes, n_edges, nblk_g);

    // ---- CSR build ----
    scan_block_kernel<<<nb_scan, SCAN_B, 0, stream>>>(deg, row_ptr, blocksums, np1);
    scan_sums_kernel<<<1, 512, 0, stream>>>(blocksums, nb_scan);
    add_offsets_kernel<<<(np1 + 255) / 256, 256, 0, stream>>>(
        row_ptr, blocksums, cursor, np1, n_nodes);
    csr_fill_kernel<<<nblk_d, 256, 0, stream>>>(src, dst, cursor, esrc, n_edges);

    // ---- fused layers ----
    const int ngroups = (n_nodes + 15) / 16;
    int fgrid = 512;
    if (fgrid > ngroups) fgrid = ngroups;

    fused_layer_kernel<<<fgrid, 512, 0, stream>>>(
        (const uint4*)bufA, row_ptr, esrc, W1hi, W1lo, b1,
        bufB, nullptr, nullptr, nullptr, wcnt + 0, n_nodes, 0);

    fused_layer_kernel<<<fgrid, 512, 0, stream>>>(
        (const uint4*)bufB, row_ptr, esrc, W2hi, W2lo, b2,
        nullptr, Wout, bout, out, wcnt + 1, n_nodes, 1);
}

// Round 5
// 620.504 us; speedup vs baseline: 2.9007x; 1.3962x over previous
//
#include <hip/hip_runtime.h>
#include <math.h>

#define D 128
#define CAP 128   // bucket capacity per node (Poisson λ=16, max-deg ~40)

typedef __attribute__((ext_vector_type(8))) short bfrag;   // 8 bf16 (4 VGPRs)
typedef __attribute__((ext_vector_type(4))) float ffrag;   // 4 fp32 acc

__device__ inline unsigned short f2bf(float f) {           // RNE fp32->bf16
    unsigned u = __float_as_uint(f);
    u += 0x7FFF + ((u >> 16) & 1);
    return (unsigned short)(u >> 16);
}
__device__ inline float bf2f(unsigned short h) {
    return __uint_as_float(((unsigned)h) << 16);
}
__device__ inline unsigned pack_bf2(float a, float b) {    // [lo=a, hi=b]
    return ((unsigned)f2bf(a)) | (((unsigned)f2bf(b)) << 16);
}

#define ACC8(u) do { \
    a0 += __uint_as_float((u).x << 16); a1 += __uint_as_float((u).x & 0xffff0000u); \
    a2 += __uint_as_float((u).y << 16); a3 += __uint_as_float((u).y & 0xffff0000u); \
    a4 += __uint_as_float((u).z << 16); a5 += __uint_as_float((u).z & 0xffff0000u); \
    a6 += __uint_as_float((u).w << 16); a7 += __uint_as_float((u).w & 0xffff0000u); \
} while (0)

// ---------------- setup1: zero cnt + split W1,W2 -> bf16 hi/lo ----------------
__global__ void setup1_kernel(const float* __restrict__ W1,
                              const float* __restrict__ W2,
                              unsigned short* __restrict__ hi1,
                              unsigned short* __restrict__ lo1,
                              unsigned short* __restrict__ hi2,
                              unsigned short* __restrict__ lo2,
                              int* __restrict__ cnt, int n_nodes, int nblk_w) {
    if ((int)blockIdx.x < nblk_w) {
        int i = blockIdx.x * blockDim.x + threadIdx.x;
        if (i < D * D) {
            float f1 = W1[i];
            unsigned short h1 = f2bf(f1);
            hi1[i] = h1;
            lo1[i] = f2bf(f1 - bf2f(h1));
            float f2 = W2[i];
            unsigned short h2 = f2bf(f2);
            hi2[i] = h2;
            lo2[i] = f2bf(f2 - bf2f(h2));
        }
    } else {
        int i = ((int)blockIdx.x - nblk_w) * blockDim.x + threadIdx.x;
        if (i < n_nodes) cnt[i] = 0;
    }
}

// ------- setup2: h0 = bf16(emb[ids])  +  one-pass padded-bucket edge fill -------
__global__ void setup2_kernel(const float* __restrict__ emb,
                              const int* __restrict__ ids,
                              uint4* __restrict__ h4,
                              const int* __restrict__ src,
                              const int* __restrict__ dst,
                              int* __restrict__ cnt,
                              int* __restrict__ bucket,
                              int n_nodes, int n_edges, int nblk_g) {
    if ((int)blockIdx.x < nblk_g) {
        int idx = blockIdx.x * blockDim.x + threadIdx.x;
        int total = n_nodes * 16;
        if (idx >= total) return;
        int node = idx >> 4;
        int c = idx & 15;
        size_t cid = (size_t)ids[node];
        const float4* s = (const float4*)(emb + cid * D) + c * 2;
        float4 v0 = s[0];
        float4 v1 = s[1];
        uint4 p;
        p.x = pack_bf2(v0.x, v0.y);
        p.y = pack_bf2(v0.z, v0.w);
        p.z = pack_bf2(v1.x, v1.y);
        p.w = pack_bf2(v1.z, v1.w);
        h4[(size_t)node * 16 + c] = p;
    } else {
        int e = ((int)blockIdx.x - nblk_g) * blockDim.x + threadIdx.x;
        if (e >= n_edges) return;
        int d = dst[e];
        int pos = atomicAdd(&cnt[d], 1);
        if (pos < CAP) bucket[(size_t)d * CAP + pos] = src[e];
        // pos >= CAP: edge not stored; agg's exact full-scan fallback covers it
    }
}

// ---------------- agg[v] = sum over bucket[v]  (bf16 in/out) ----------------
// One wave per node. 16 lanes cover a 256B row with uint4 loads; group g=lane>>4.
// All <=64 edge indices loaded in ONE coalesced read, broadcast via shfl
// (wave-uniform trip count). 8 predicated gathers in flight per group
// (round-4-verified pattern). deg>CAP (~never): exact full edge scan.
__global__ __launch_bounds__(256) void agg_kernel(
        const uint4* __restrict__ h4,
        const int* __restrict__ cnt,
        const int* __restrict__ bucket,
        const int* __restrict__ src,
        const int* __restrict__ dst,
        uint4* __restrict__ agg4,
        int n_nodes, int n_edges) {
    int node = blockIdx.x * 4 + (threadIdx.x >> 6);
    int lane = threadIdx.x & 63;
    if (node >= n_nodes) return;
    const int c = lane & 15;     // uint4 chunk within row (dims c*8 .. c*8+7)
    const int g = lane >> 4;     // edge group 0..3
    int deg = cnt[node];

    float a0 = 0.f, a1 = 0.f, a2 = 0.f, a3 = 0.f;
    float a4 = 0.f, a5 = 0.f, a6 = 0.f, a7 = 0.f;

    if (deg <= CAP) {
        const int beg = node * CAP;
        int myidx = 0;
        if (lane < deg) myidx = bucket[beg + lane];   // coalesced 64-edge load

        int nfast = deg < 64 ? deg : 64;
        for (int base = 0; base < nfast; base += 32) {  // UNIFORM trip count
            int p0 = base + g;           // <= 35
            int p4 = p0 + 16;            // <= 51; +12 <= 63: full-wave shfl ok
            int s0 = __shfl(myidx, p0, 64);
            int s1 = __shfl(myidx, p0 + 4, 64);
            int s2 = __shfl(myidx, p0 + 8, 64);
            int s3 = __shfl(myidx, p0 + 12, 64);
            int s4i = __shfl(myidx, p4, 64);
            int s5 = __shfl(myidx, p4 + 4, 64);
            int s6 = __shfl(myidx, p4 + 8, 64);
            int s7 = __shfl(myidx, p4 + 12, 64);
            bool v0 = p0 < nfast;
            bool v1 = (p0 + 4) < nfast;
            bool v2 = (p0 + 8) < nfast;
            bool v3 = (p0 + 12) < nfast;
            bool v4 = p4 < nfast;
            bool v5 = (p4 + 4) < nfast;
            bool v6 = (p4 + 8) < nfast;
            bool v7 = (p4 + 12) < nfast;
            uint4 u0, u1, u2, u3, u4, u5, u6, u7;
            if (v0) u0 = h4[(size_t)s0 * 16 + c];
            if (v1) u1 = h4[(size_t)s1 * 16 + c];
            if (v2) u2 = h4[(size_t)s2 * 16 + c];
            if (v3) u3 = h4[(size_t)s3 * 16 + c];
            if (v4) u4 = h4[(size_t)s4i * 16 + c];
            if (v5) u5 = h4[(size_t)s5 * 16 + c];
            if (v6) u6 = h4[(size_t)s6 * 16 + c];
            if (v7) u7 = h4[(size_t)s7 * 16 + c];
            if (v0) ACC8(u0);
            if (v1) ACC8(u1);
            if (v2) ACC8(u2);
            if (v3) ACC8(u3);
            if (v4) ACC8(u4);
            if (v5) ACC8(u5);
            if (v6) ACC8(u6);
            if (v7) ACC8(u7);
        }
        for (int i = 64 + g; i < deg; i += 4) {   // 64 < deg <= CAP: ~never
            uint4 u = h4[(size_t)bucket[beg + i] * 16 + c];
            ACC8(u);
        }
    } else {
        // overflow fallback (exact, probability ~0): scan all edges
        for (int e = g; e < n_edges; e += 4) {
            if (dst[e] == node) {
                uint4 u = h4[(size_t)src[e] * 16 + c];
                ACC8(u);
            }
        }
    }

    // combine the 4 lane groups (lanes c, c+16, c+32, c+48 hold same dims)
    a0 += __shfl_xor(a0, 16, 64); a0 += __shfl_xor(a0, 32, 64);
    a1 += __shfl_xor(a1, 16, 64); a1 += __shfl_xor(a1, 32, 64);
    a2 += __shfl_xor(a2, 16, 64); a2 += __shfl_xor(a2, 32, 64);
    a3 += __shfl_xor(a3, 16, 64); a3 += __shfl_xor(a3, 32, 64);
    a4 += __shfl_xor(a4, 16, 64); a4 += __shfl_xor(a4, 32, 64);
    a5 += __shfl_xor(a5, 16, 64); a5 += __shfl_xor(a5, 32, 64);
    a6 += __shfl_xor(a6, 16, 64); a6 += __shfl_xor(a6, 32, 64);
    a7 += __shfl_xor(a7, 16, 64); a7 += __shfl_xor(a7, 32, 64);

    if (g == 0) {
        uint4 r;
        r.x = pack_bf2(a0, a1);
        r.y = pack_bf2(a2, a3);
        r.z = pack_bf2(a4, a5);
        r.w = pack_bf2(a6, a7);
        agg4[(size_t)node * 16 + c] = r;
    }
}

// ---------------- y = relu(x @ W^T + b) via bf16 MFMA (round-2 verified) ---------
__global__ __launch_bounds__(256) void linear_mfma_kernel(
        const unsigned short* __restrict__ x,
        const unsigned short* __restrict__ Whi,
        const unsigned short* __restrict__ Wlo,
        const float* __restrict__ b,
        unsigned short* __restrict__ y,
        const float* __restrict__ wout,
        const float* __restrict__ bout,
        float* __restrict__ outp,
        int n_nodes, int fuse_out) {
    __shared__ __align__(16) unsigned short sW[2][D][136];   // 69632 B

    {   // cooperative stage: 2048 chunks of 16B per matrix, 256 threads x 8
        const uint4* Wh4 = (const uint4*)Whi;
        const uint4* Wl4 = (const uint4*)Wlo;
        #pragma unroll
        for (int j = 0; j < 8; ++j) {
            int ch = (int)threadIdx.x + j * 256;
            int row = ch >> 4, k8 = ch & 15;
            *(uint4*)&sW[0][row][k8 * 8] = Wh4[ch];
            *(uint4*)&sW[1][row][k8 * 8] = Wl4[ch];
        }
    }
    __syncthreads();

    const int lane = threadIdx.x & 63;
    const int col  = lane & 15;        // m (A) / n (B) index
    const int quad = lane >> 4;        // k-chunk selector
    const int wave = blockIdx.x * 4 + (threadIdx.x >> 6);
    const int nwaves = gridDim.x * 4;
    const int ngroups = (n_nodes + 15) >> 4;

    float bvals[8], wvals[8];
    #pragma unroll
    for (int nt = 0; nt < 8; ++nt) {
        bvals[nt] = b[nt * 16 + col];
        wvals[nt] = fuse_out ? wout[nt * 16 + col] : 0.f;
    }
    const float bout0 = fuse_out ? bout[0] : 0.f;

    for (int g = wave; g < ngroups; g += nwaves) {
        int node = g * 16 + col;
        int nload = node < n_nodes ? node : (n_nodes - 1);

        bfrag a[4];
        #pragma unroll
        for (int kt = 0; kt < 4; ++kt)
            a[kt] = *(const bfrag*)(x + (size_t)nload * D + kt * 32 + quad * 8);

        float part0 = 0.f, part1 = 0.f, part2 = 0.f, part3 = 0.f;

        #pragma unroll
        for (int nt = 0; nt < 8; ++nt) {
            ffrag c = {0.f, 0.f, 0.f, 0.f};
            #pragma unroll
            for (int kt = 0; kt < 4; ++kt) {
                bfrag bh = *(const bfrag*)&sW[0][nt * 16 + col][kt * 32 + quad * 8];
                bfrag bl = *(const bfrag*)&sW[1][nt * 16 + col][kt * 32 + quad * 8];
                c = __builtin_amdgcn_mfma_f32_16x16x32_bf16(a[kt], bh, c, 0, 0, 0);
                c = __builtin_amdgcn_mfma_f32_16x16x32_bf16(a[kt], bl, c, 0, 0, 0);
            }
            // C layout: value r is C[row = quad*4 + r][col]
            if (fuse_out) {
                part0 += fmaxf(c[0] + bvals[nt], 0.f) * wvals[nt];
                part1 += fmaxf(c[1] + bvals[nt], 0.f) * wvals[nt];
                part2 += fmaxf(c[2] + bvals[nt], 0.f) * wvals[nt];
                part3 += fmaxf(c[3] + bvals[nt], 0.f) * wvals[nt];
            } else {
                #pragma unroll
                for (int r = 0; r < 4; ++r) {
                    int onode = g * 16 + quad * 4 + r;
                    if (onode < n_nodes)
                        y[(size_t)onode * D + nt * 16 + col] =
                            f2bf(fmaxf(c[r] + bvals[nt], 0.f));
                }
            }
        }

        if (fuse_out) {
            float part[4] = {part0, part1, part2, part3};
            #pragma unroll
            for (int r = 0; r < 4; ++r) {
                float s = part[r];
                s += __shfl_xor(s, 1, 64);
                s += __shfl_xor(s, 2, 64);
                s += __shfl_xor(s, 4, 64);
                s += __shfl_xor(s, 8, 64);   // reduce over 16 cols within quad
                int onode = g * 16 + quad * 4 + r;
                if (col == 0 && onode < n_nodes)
                    outp[onode] = 1.0f / (1.0f + expf(-(s + bout0)));
            }
        }
    }
}

// ================== host launcher ==================

extern "C" void kernel_launch(void* const* d_in, const int* in_sizes, int n_in,
                              void* d_out, int out_size, void* d_ws, size_t ws_size,
                              hipStream_t stream) {
    const int*   cncpt_ids = (const int*)d_in[0];
    const int*   src       = (const int*)d_in[1];
    const int*   dst       = (const int*)d_in[2];
    const float* emb       = (const float*)d_in[3];
    const float* W1        = (const float*)d_in[4];
    const float* b1        = (const float*)d_in[5];
    const float* W2        = (const float*)d_in[6];
    const float* b2        = (const float*)d_in[7];
    const float* Wout      = (const float*)d_in[8];
    const float* bout      = (const float*)d_in[9];
    float* out = (float*)d_out;

    const int n_nodes = in_sizes[0];
    const int n_edges = in_sizes[1];

    // ---- workspace carve-up ----
    unsigned short* bufA = (unsigned short*)d_ws;          // N*D bf16
    unsigned short* bufB = bufA + (size_t)n_nodes * D;     // N*D bf16
    int*   cnt    = (int*)(bufB + (size_t)n_nodes * D);    // N ints
    int*   bucket = cnt + n_nodes;                         // N*CAP ints (51.2 MB)
    size_t walign = ((size_t)(bucket + (size_t)n_nodes * CAP) + 15) & ~(size_t)15;
    unsigned short* W1hi = (unsigned short*)walign;        // D*D each
    unsigned short* W1lo = W1hi + D * D;
    unsigned short* W2hi = W1lo + D * D;
    unsigned short* W2lo = W2hi + D * D;

    // ---- setup1: zero cnt + weight splits ----
    const int nblk_w = (D * D + 255) / 256;
    const int nblk_z = (n_nodes + 255) / 256;
    setup1_kernel<<<nblk_w + nblk_z, 256, 0, stream>>>(
        W1, W2, W1hi, W1lo, W2hi, W2lo, cnt, n_nodes, nblk_w);

    // ---- setup2: gather h0 + one-pass bucket fill ----
    const int nblk_g = (n_nodes * 16 + 255) / 256;
    const int nblk_d = (n_edges + 255) / 256;
    setup2_kernel<<<nblk_g + nblk_d, 256, 0, stream>>>(
        emb, cncpt_ids, (uint4*)bufA, src, dst, cnt, bucket,
        n_nodes, n_edges, nblk_g);

    const int agg_grid = (n_nodes + 3) / 4;
    const int ngroups = (n_nodes + 15) / 16;
    const int lin_grid = (ngroups + 7) / 8;   // 4 waves/block, ~2 groups/wave

    // ---- layer 1 ----
    agg_kernel<<<agg_grid, 256, 0, stream>>>(
        (const uint4*)bufA, cnt, bucket, src, dst, (uint4*)bufB,
        n_nodes, n_edges);
    linear_mfma_kernel<<<lin_grid, 256, 0, stream>>>(
        bufB, W1hi, W1lo, b1, bufA, nullptr, nullptr, nullptr, n_nodes, 0);

    // ---- layer 2 + fused output head ----
    agg_kernel<<<agg_grid, 256, 0, stream>>>(
        (const uint4*)bufA, cnt, bucket, src, dst, (uint4*)bufB,
        n_nodes, n_edges);
    linear_mfma_kernel<<<lin_grid, 256, 0, stream>>>(
        bufB, W2hi, W2lo, b2, nullptr, Wout, bout, out, n_nodes, 1);
}